// Round 17
// baseline (94.897 us; speedup 1.0000x reference)
//
#include <hip/hip_runtime.h>
#include <hip/hip_bf16.h>
#include <math.h>

#define HH 8
#define CC 32
#define DD 128
#define HC 256
#define II 128
#define LL 256
#define NROW (II*LL)   // 32768
#define LN_EPS 1e-5f
#define LOG2E 1.4426950408889634f

typedef float f32x4 __attribute__((ext_vector_type(4)));
typedef short short8 __attribute__((ext_vector_type(8)));
typedef short short4v __attribute__((ext_vector_type(4)));
typedef unsigned short us;

static __device__ __forceinline__ us bfc(float x) {
    return __builtin_bit_cast(us, __float2bfloat16(x));
}
static __device__ __forceinline__ float bf2f(us h) {
    return __builtin_bit_cast(float, ((unsigned int)h) << 16);
}
// global -> LDS async 16B/lane; LDS dest = uniform base + lane*16 (linear).
static __device__ __forceinline__ void gload_lds16(const us* g, us* l) {
    __builtin_amdgcn_global_load_lds(
        (const __attribute__((address_space(1))) unsigned int*)g,
        (__attribute__((address_space(3))) unsigned int*)l,
        16, 0, 0);
}

// ---------------- K1: LayerNorm, 1 wave per row, bf16 out -------------------
__global__ __launch_bounds__(256) void k_ln(const float* __restrict__ z,
                                            const float* __restrict__ gamma,
                                            const float* __restrict__ beta,
                                            us* __restrict__ zn)
{
    const int t = threadIdx.x;
    const int row = blockIdx.x * 4 + (t >> 6);
    const int lane = t & 63;
    float2 x = *(const float2*)(z + (size_t)row * DD + lane * 2);
    float s = x.x + x.y;
    float s2 = x.x * x.x + x.y * x.y;
#pragma unroll
    for (int off = 1; off < 64; off <<= 1) {
        s  += __shfl_xor(s, off, 64);
        s2 += __shfl_xor(s2, off, 64);
    }
    float mu = s * (1.0f / DD);
    float var = s2 * (1.0f / DD) - mu * mu;
    float rstd = rsqrtf(var + LN_EPS);
    float2 gm = *(const float2*)(gamma + lane * 2);
    float2 bt = *(const float2*)(beta + lane * 2);
    float y0 = (x.x - mu) * rstd * gm.x + bt.x;
    float y1 = (x.y - mu) * rstd * gm.y + bt.y;
    unsigned int pk = (unsigned int)bfc(y0) | ((unsigned int)bfc(y1) << 16);
    ((unsigned int*)zn)[(size_t)row * 64 + lane] = pk;
}

// ---------------- K1b: weight prep ------------------------------------------
// Q weights additionally scaled by LOG2E (exp -> exp2 folding in k_attn).
__global__ __launch_bounds__(256) void k_wprep(const float* __restrict__ Wq,
                                               const float* __restrict__ Wk,
                                               const float* __restrict__ Wv,
                                               const float* __restrict__ Wg,
                                               const float* __restrict__ Wf,
                                               us* __restrict__ F,
                                               us* __restrict__ WfpH,
                                               us* __restrict__ WfpL)
{
    const int bid = blockIdx.x;
    if (bid < 128) {
        const int mat = bid >> 5;
        const float* W = (mat == 0) ? Wq : (mat == 1) ? Wk : (mat == 2) ? Wv : Wg;
        const float scale = (mat == 0) ? 0.35355339059327373f * LOG2E : 1.0f;
        int base = (bid & 31) * 1024 + threadIdx.x * 4;
        float4 wv = *(const float4*)(W + base);
        int k = base >> 8, n0 = base & 255;
        int ks = k >> 5, kk = k & 31;
        int slot = ((kk >> 4) << 2) | (kk & 3);
        int gg = (kk >> 2) & 3;
        float vals[4] = {wv.x, wv.y, wv.z, wv.w};
        us* Fb = F + mat * 32768;
#pragma unroll
        for (int e = 0; e < 4; ++e) {
            int n = n0 + e;
            int lane = (n & 15) | (gg << 4);
            Fb[((size_t)(ks * 16 + (n >> 4)) * 64 + lane) * 8 + slot] = bfc(vals[e] * scale);
        }
    } else {
        int idx = ((bid - 128) * 256 + threadIdx.x) * 4;
#pragma unroll
        for (int e = 0; e < 4; ++e, ++idx) {
            int k = idx >> 7, n = idx & 127;
            float w = Wf[idx];
            us hi = bfc(w);
            us lo = bfc(w - bf2f(hi));
            int kk = k & 31;
            int g = (kk >> 2) & 3, b = kk >> 4, j0 = kk & 3;
            int lane = (n & 15) | (g << 4);
            size_t dst = ((size_t)((k >> 5) * 8 + (n >> 4)) * 64 + lane) * 8 + b * 4 + j0;
            WfpH[dst] = hi;
            WfpL[dst] = lo;
        }
    }
}

// ---------------- K2: projections via bf16 MFMA, 64-row tiles ---------------
__global__ __launch_bounds__(256, 6) void k_proj(const us* __restrict__ zn,
                                                 const us* __restrict__ F,
                                                 const float* __restrict__ bg,
                                                 us* __restrict__ Qf,
                                                 us* __restrict__ Kf,
                                                 us* __restrict__ Vtf,
                                                 us* __restrict__ Pg)
{
    const int rb = blockIdx.x, cb = blockIdx.y, t = threadIdx.x;
    const int m0 = rb * 64, n0 = cb * 128;
    const int mat = n0 >> 8, lc0 = n0 & 255;
    __shared__ us A[64][136];   // perm-k A tile; reused as C-stage

#pragma unroll
    for (int e = 0; e < 4; ++e) {
        int cid = e * 256 + t;
        int row = cid >> 4, c = cid & 15;
        uint4 q = *(const uint4*)(zn + (size_t)(m0 + row) * DD + c * 8);
        int ks = c >> 2, cc = c & 3;
        int fe = (cc & 1) * 16 + (cc >> 1) * 4;
        *(uint2*)&A[row][ks * 32 + fe]     = make_uint2(q.x, q.y);
        *(uint2*)&A[row][ks * 32 + fe + 8] = make_uint2(q.z, q.w);
    }
    __syncthreads();

    const int lane = t & 63, w = t >> 6;
    const int wm = w & 1, wn = w >> 1;
    const int l0 = lane & 15, g = lane >> 4;
    const us* Fb = F + mat * 32768 + ((size_t)((lc0 >> 4) + wn * 4) * 64 + lane) * 8;
    f32x4 acc[2][4];
#pragma unroll
    for (int a = 0; a < 2; ++a)
#pragma unroll
        for (int b = 0; b < 4; ++b) acc[a][b] = (f32x4){0, 0, 0, 0};

#pragma unroll
    for (int ks = 0; ks < 4; ++ks) {
        short8 af[2], bfr[4];
#pragma unroll
        for (int mf = 0; mf < 2; ++mf)
            af[mf] = *(const short8*)&A[wm * 32 + mf * 16 + l0][ks * 32 + 8 * g];
#pragma unroll
        for (int nf = 0; nf < 4; ++nf)
            bfr[nf] = *(const short8*)(Fb + (size_t)(ks * 16 + nf) * 512);
#pragma unroll
        for (int mf = 0; mf < 2; ++mf)
#pragma unroll
            for (int nf = 0; nf < 4; ++nf)
                acc[mf][nf] = __builtin_amdgcn_mfma_f32_16x16x32_bf16(af[mf], bfr[nf], acc[mf][nf], 0, 0, 0);
    }

    __syncthreads();   // all A reads done; reuse as C-stage (plain row/col)
    us (*Cs)[136] = A;
#pragma unroll
    for (int nf = 0; nf < 4; ++nf) {
        int lcol = wn * 64 + nf * 16 + l0;
        float bgv = (mat == 3) ? bg[lc0 + lcol] : 0.0f;
#pragma unroll
        for (int mf = 0; mf < 2; ++mf) {
#pragma unroll
            for (int r = 0; r < 4; ++r) {
                float v = acc[mf][nf][r];
                if (mat == 3) v = 1.0f / (1.0f + __expf(-(v + bgv)));
                Cs[wm * 32 + mf * 16 + 4 * g + r][lcol] = bfc(v);
            }
        }
    }
    __syncthreads();

    const int i = m0 >> 8;
    const int ktbase = (m0 & 255) >> 4;     // 0,4,8,12
    const int pbase  = (m0 & 255) >> 5;     // 0,2,4,6
    if (mat <= 1) {
        us* Dst = (mat == 0) ? Qf : Kf;
#pragma unroll
        for (int e = 0; e < 4; ++e) {
            int sub = e * 256 + t;                  // 0..1023
            int lane2 = sub & 63;
            int l0b = lane2 & 15, gb = lane2 >> 4;
            int rest = sub >> 6;                    // 0..15
            int hl = rest & 3, ktl = rest >> 2;     // 4 heads, 4 kt
            int hglob = (lc0 >> 5) + hl;
            int kt = ktbase + ktl;
            short8 vv = *(const short8*)&Cs[ktl * 16 + l0b][hl * 32 + 8 * gb];
            *(short8*)(Dst + (((size_t)(i * 8 + hglob) * 16 + kt) * 64 + lane2) * 8) = vv;
        }
    } else if (mat == 2) {
#pragma unroll
        for (int e = 0; e < 4; ++e) {
            int sub = e * 256 + t;                  // 0..1023
            int lane2 = sub & 63;
            int l0b = lane2 & 15, gb = lane2 >> 4;
            int rest = sub >> 6;                    // 0..15
            int ct = rest & 1, pl = (rest >> 1) & 1, hl = rest >> 2;
            int hglob = (lc0 >> 5) + hl;
            int p = pbase + pl;
            int col = hl * 32 + ct * 16 + l0b;
            us vals[8];
#pragma unroll
            for (int j = 0; j < 8; ++j) {
                int kk = 4 * gb + (j & 3) + 16 * (j >> 2);
                vals[j] = Cs[pl * 32 + kk][col];
            }
            *(short8*)(Vtf + ((((size_t)(i * 8 + hglob) * 8 + p) * 2 + ct) * 64 + lane2) * 8)
                = *(short8*)vals;
        }
    } else {
#pragma unroll
        for (int e = 0; e < 4; ++e) {
            int cid = e * 256 + t;
            int row = cid >> 4, c = cid & 15;
            short8 vv = *(const short8*)&Cs[row][c * 8];
            *(short8*)(Pg + (size_t)(m0 + row) * 256 + lc0 + c * 8) = vv;
        }
    }
}

// ---------------- K3: MFMA attention, 512 threads = 8 waves per (i,h) -------
// One block per ih: 8 waves x 32 q-rows cover all 256 q. Per-wave structure
// identical to the proven 2-qt version; K+V staged ONCE per (i,h).
// LDS 33.8KB -> 4 blocks/CU x 8 waves = 32 waves/CU (100% cap).
__global__ __launch_bounds__(512) void k_attn(const us* __restrict__ Qf,
                                              const us* __restrict__ Kf,
                                              const us* __restrict__ Vtf,
                                              const us* __restrict__ Pg,
                                              us* __restrict__ Po,
                                              const float* __restrict__ djk,
                                              const float* __restrict__ Wd,
                                              const float* __restrict__ mask)
{
    const int ih = blockIdx.x;          // 1024 blocks
    const int i = ih >> 3, h = ih & 7;
    const int t = threadIdx.x;          // 0..511
    const int lane = t & 63, w = t >> 6;    // w in [0,8)
    const int l0 = lane & 15, g = lane >> 4;
    const int q0 = w * 32;

    __shared__ us Kl[16 * 512];     // 16 K-frag tiles, linear (16KB); reused as gs
    __shared__ us Vl[16 * 512];     // 16 V-frag tiles, linear (16KB)
    __shared__ float madd[LL];      // log2e-scaled mask bias

    const us* Kb = Kf + (size_t)ih * 8192;
    const us* Vb = Vtf + (size_t)ih * 8192;

    // stage K+V: wave w -> tiles 2w, 2w+1 of each (async direct-to-LDS)
    {
        int tile = w * 2;
        gload_lds16(Kb + (size_t)tile * 512 + lane * 8, &Kl[tile * 512]);
        gload_lds16(Kb + (size_t)(tile + 1) * 512 + lane * 8, &Kl[(tile + 1) * 512]);
        gload_lds16(Vb + (size_t)tile * 512 + lane * 8, &Vl[tile * 512]);
        gload_lds16(Vb + (size_t)(tile + 1) * 512 + lane * 8, &Vl[(tile + 1) * 512]);
    }
    if (t < LL) madd[t] = (LOG2E * 1e9f) * (mask[i * LL + t] - 1.0f);

    const float wd = Wd[h] * LOG2E;
    short8 qfr[2];
    int qrow[2];
    const float* djkq[2];
#pragma unroll
    for (int qt = 0; qt < 2; ++qt) {
        qfr[qt] = *(const short8*)(Qf + (size_t)ih * 8192 + ((size_t)(w * 2 + qt) * 64 + lane) * 8);
        qrow[qt] = q0 + qt * 16 + l0;
        djkq[qt] = djk + (size_t)qrow[qt] * LL;
    }
    __syncthreads();

    f32x4 oacc[2][2];
#pragma unroll
    for (int ct = 0; ct < 2; ++ct)
#pragma unroll
        for (int qt = 0; qt < 2; ++qt) oacc[ct][qt] = (f32x4){0, 0, 0, 0};
    float ssum[2] = {0, 0};

    for (int p = 0; p < 8; ++p) {
        short8 pfv[2];
#pragma unroll
        for (int hf = 0; hf < 2; ++hf) {
            const int kt = 2 * p + hf;
            short8 kfr = *(const short8*)&Kl[kt * 512 + lane * 8];
            f32x4 mvv = *(const f32x4*)&madd[kt * 16 + 4 * g];
#pragma unroll
            for (int qt = 0; qt < 2; ++qt) {
                f32x4 z4 = {0, 0, 0, 0};
                f32x4 s = __builtin_amdgcn_mfma_f32_16x16x32_bf16(kfr, qfr[qt], z4, 0, 0, 0);
                f32x4 dv = *(const f32x4*)(djkq[qt] + kt * 16 + 4 * g);
                float p0 = __builtin_amdgcn_exp2f(s[0] + wd * dv.x + mvv.x);
                float p1 = __builtin_amdgcn_exp2f(s[1] + wd * dv.y + mvv.y);
                float p2 = __builtin_amdgcn_exp2f(s[2] + wd * dv.z + mvv.z);
                float p3 = __builtin_amdgcn_exp2f(s[3] + wd * dv.w + mvv.w);
                ssum[qt] += (p0 + p1) + (p2 + p3);
                pfv[qt][hf * 4 + 0] = (short)bfc(p0);
                pfv[qt][hf * 4 + 1] = (short)bfc(p1);
                pfv[qt][hf * 4 + 2] = (short)bfc(p2);
                pfv[qt][hf * 4 + 3] = (short)bfc(p3);
            }
        }
#pragma unroll
        for (int ct = 0; ct < 2; ++ct) {
            short8 vfr = *(const short8*)&Vl[(p * 2 + ct) * 512 + lane * 8];
#pragma unroll
            for (int qt = 0; qt < 2; ++qt)
                oacc[ct][qt] = __builtin_amdgcn_mfma_f32_16x16x32_bf16(vfr, pfv[qt], oacc[ct][qt], 0, 0, 0);
        }
    }

    // epilogue: row sums, gate, LDS transpose (reuse Kl), head-major write
    __syncthreads();   // all Kl/Vl reads complete before reuse
    us (*gs)[40] = (us (*)[40])Kl;  // 256 x 40 = 20KB, fits Kl+Vl region
#pragma unroll
    for (int qt = 0; qt < 2; ++qt) {
        float s = ssum[qt];
        s += __shfl_xor(s, 16, 64);
        s += __shfl_xor(s, 32, 64);
        float inv = 1.0f / s;
        const us* gb = Pg + (size_t)(i * LL + qrow[qt]) * 256 + h * CC;
#pragma unroll
        for (int ct = 0; ct < 2; ++ct) {
            short4v gv = *(const short4v*)(gb + ct * 16 + 4 * g);
            f32x4 ov = oacc[ct][qt];
            short4v res;
            res.x = (short)bfc(bf2f((us)gv.x) * ov.x * inv);
            res.y = (short)bfc(bf2f((us)gv.y) * ov.y * inv);
            res.z = (short)bfc(bf2f((us)gv.z) * ov.z * inv);
            res.w = (short)bfc(bf2f((us)gv.w) * ov.w * inv);
            *(short4v*)&gs[q0 + qt * 16 + l0][ct * 16 + 4 * g] = res;
        }
    }
    __syncthreads();
#pragma unroll
    for (int e = 0; e < 2; ++e) {
        int cid = e * 512 + t;           // 0..1023
        int row = cid >> 2, c = cid & 3;
        short8 vv = *(const short8*)&gs[row][c * 8];
        *(short8*)(Po + ((size_t)h * NROW + (size_t)i * LL + row) * 32 + c * 8) = vv;
    }
}

// ---------------- K4: out = gated @ (WfH + WfL) + bf, x mask (MFMA) ---------
// Po is head-major: Po[h][grow][32].
__global__ __launch_bounds__(256) void k_out(const us* __restrict__ Po,
                                             const us* __restrict__ WfpH,
                                             const us* __restrict__ WfpL,
                                             const float* __restrict__ bf_,
                                             const float* __restrict__ mask,
                                             float* __restrict__ out)
{
    const int t = threadIdx.x;
    const int m0 = blockIdx.x * 64;
    __shared__ us A[64][264];
#pragma unroll
    for (int e = 0; e < 8; ++e) {
        int cid = e * 256 + t;
        int row = cid >> 5, c = cid & 31;          // c*8 = global k chunk
        int hh = c >> 2, cc = c & 3;               // head, chunk-within-head
        uint4 q = *(const uint4*)(Po + ((size_t)hh * NROW + m0 + row) * 32 + cc * 8);
        int ksb = c >> 2, cc2 = c & 3;
        int fe = (cc2 & 1) * 16 + (cc2 >> 1) * 4;
        *(uint2*)&A[row][ksb * 32 + fe]     = make_uint2(q.x, q.y);
        *(uint2*)&A[row][ksb * 32 + fe + 8] = make_uint2(q.z, q.w);
    }
    __syncthreads();
    const int lane = t & 63, w = t >> 6;
    const int l0 = lane & 15, g = lane >> 4;
    f32x4 acc[8];
#pragma unroll
    for (int nf = 0; nf < 8; ++nf) acc[nf] = (f32x4){0, 0, 0, 0};

#pragma unroll
    for (int ksb = 0; ksb < 8; ++ksb) {
        short8 af = *(const short8*)&A[w * 16 + l0][ksb * 32 + 8 * g];
#pragma unroll
        for (int nf = 0; nf < 8; ++nf) {
            short8 bh = *(const short8*)(WfpH + ((size_t)(ksb * 8 + nf) * 64 + lane) * 8);
            short8 bl = *(const short8*)(WfpL + ((size_t)(ksb * 8 + nf) * 64 + lane) * 8);
            acc[nf] = __builtin_amdgcn_mfma_f32_16x16x32_bf16(af, bh, acc[nf], 0, 0, 0);
            acc[nf] = __builtin_amdgcn_mfma_f32_16x16x32_bf16(af, bl, acc[nf], 0, 0, 0);
        }
    }
    float maskv[4];
    int rowm[4];
#pragma unroll
    for (int r = 0; r < 4; ++r) {
        rowm[r] = m0 + w * 16 + 4 * g + r;
        maskv[r] = mask[rowm[r]];
    }
#pragma unroll
    for (int nf = 0; nf < 8; ++nf) {
        int n = nf * 16 + l0;
        float bfv = bf_[n];
#pragma unroll
        for (int r = 0; r < 4; ++r)
            out[(size_t)rowm[r] * DD + n] = (acc[nf][r] + bfv) * maskv[r];
    }
}

extern "C" void kernel_launch(void* const* d_in, const int* in_sizes, int n_in,
                              void* d_out, int out_size, void* d_ws, size_t ws_size,
                              hipStream_t stream)
{
    const float* z     = (const float*)d_in[0];
    const float* djk   = (const float*)d_in[1];
    const float* mask  = (const float*)d_in[2];
    const float* gamma = (const float*)d_in[3];
    const float* beta  = (const float*)d_in[4];
    const float* Wq    = (const float*)d_in[5];
    const float* Wk    = (const float*)d_in[6];
    const float* Wv    = (const float*)d_in[7];
    // d_in[8] = Wb: constant along softmax axis -> cancels exactly.
    const float* Wd    = (const float*)d_in[9];
    const float* Wg    = (const float*)d_in[10];
    const float* bg    = (const float*)d_in[11];
    const float* Wf    = (const float*)d_in[12];
    const float* bf_   = (const float*)d_in[13];
    float* out = (float*)d_out;

    us* zn   = (us*)d_ws;                         // 8.4 MB
    us* Qf   = zn   + (size_t)NROW * DD;          // 16.8 MB
    us* Kf   = Qf   + (size_t)1024 * 8192;        // 16.8 MB
    us* Vtf  = Kf   + (size_t)1024 * 8192;        // 16.8 MB
    us* Pg   = Vtf  + (size_t)1024 * 8192;        // 16.8 MB
    us* Po   = Pg   + (size_t)NROW * 256;         // 16.8 MB (head-major)
    us* WfpH = Po   + (size_t)NROW * 256;         // 64 KB
    us* WfpL = WfpH + 256 * 128;                  // 64 KB
    us* F    = WfpL + 256 * 128;                  // 256 KB

    k_ln   <<<NROW / 4, 256, 0, stream>>>(z, gamma, beta, zn);
    k_wprep<<<160, 256, 0, stream>>>(Wq, Wk, Wv, Wg, Wf, F, WfpH, WfpL);
    k_proj <<<dim3(NROW / 64, 8), 256, 0, stream>>>(zn, F, bg, Qf, Kf, Vtf, Pg);
    k_attn <<<1024, 512, 0, stream>>>(Qf, Kf, Vtf, Pg, Po, djk, Wd, mask);
    k_out  <<<NROW / 64, 256, 0, stream>>>(Po, WfpH, WfpL, bf_, mask, out);
}

// Round 18
// 89.544 us; speedup vs baseline: 1.0598x; 1.0598x over previous
//
#include <hip/hip_runtime.h>
#include <hip/hip_bf16.h>
#include <math.h>

#define HH 8
#define CC 32
#define DD 128
#define HC 256
#define II 128
#define LL 256
#define NROW (II*LL)   // 32768
#define LN_EPS 1e-5f
#define LOG2E 1.4426950408889634f

typedef float f32x4 __attribute__((ext_vector_type(4)));
typedef short short8 __attribute__((ext_vector_type(8)));
typedef short short4v __attribute__((ext_vector_type(4)));
typedef unsigned short us;

static __device__ __forceinline__ us bfc(float x) {
    return __builtin_bit_cast(us, __float2bfloat16(x));
}
static __device__ __forceinline__ float bf2f(us h) {
    return __builtin_bit_cast(float, ((unsigned int)h) << 16);
}
// global -> LDS async 16B/lane; LDS dest = uniform base + lane*16 (linear).
static __device__ __forceinline__ void gload_lds16(const us* g, us* l) {
    __builtin_amdgcn_global_load_lds(
        (const __attribute__((address_space(1))) unsigned int*)g,
        (__attribute__((address_space(3))) unsigned int*)l,
        16, 0, 0);
}

// ---------------- K1: LayerNorm, 1 wave per row, bf16 out -------------------
__global__ __launch_bounds__(256) void k_ln(const float* __restrict__ z,
                                            const float* __restrict__ gamma,
                                            const float* __restrict__ beta,
                                            us* __restrict__ zn)
{
    const int t = threadIdx.x;
    const int row = blockIdx.x * 4 + (t >> 6);
    const int lane = t & 63;
    float2 x = *(const float2*)(z + (size_t)row * DD + lane * 2);
    float s = x.x + x.y;
    float s2 = x.x * x.x + x.y * x.y;
#pragma unroll
    for (int off = 1; off < 64; off <<= 1) {
        s  += __shfl_xor(s, off, 64);
        s2 += __shfl_xor(s2, off, 64);
    }
    float mu = s * (1.0f / DD);
    float var = s2 * (1.0f / DD) - mu * mu;
    float rstd = rsqrtf(var + LN_EPS);
    float2 gm = *(const float2*)(gamma + lane * 2);
    float2 bt = *(const float2*)(beta + lane * 2);
    float y0 = (x.x - mu) * rstd * gm.x + bt.x;
    float y1 = (x.y - mu) * rstd * gm.y + bt.y;
    unsigned int pk = (unsigned int)bfc(y0) | ((unsigned int)bfc(y1) << 16);
    ((unsigned int*)zn)[(size_t)row * 64 + lane] = pk;
}

// ---------------- K1b: weight prep ------------------------------------------
// Q weights additionally scaled by LOG2E (exp -> exp2 folding in k_attn).
__global__ __launch_bounds__(256) void k_wprep(const float* __restrict__ Wq,
                                               const float* __restrict__ Wk,
                                               const float* __restrict__ Wv,
                                               const float* __restrict__ Wg,
                                               const float* __restrict__ Wf,
                                               us* __restrict__ F,
                                               us* __restrict__ WfpH,
                                               us* __restrict__ WfpL)
{
    const int bid = blockIdx.x;
    if (bid < 128) {
        const int mat = bid >> 5;
        const float* W = (mat == 0) ? Wq : (mat == 1) ? Wk : (mat == 2) ? Wv : Wg;
        const float scale = (mat == 0) ? 0.35355339059327373f * LOG2E : 1.0f;
        int base = (bid & 31) * 1024 + threadIdx.x * 4;
        float4 wv = *(const float4*)(W + base);
        int k = base >> 8, n0 = base & 255;
        int ks = k >> 5, kk = k & 31;
        int slot = ((kk >> 4) << 2) | (kk & 3);
        int gg = (kk >> 2) & 3;
        float vals[4] = {wv.x, wv.y, wv.z, wv.w};
        us* Fb = F + mat * 32768;
#pragma unroll
        for (int e = 0; e < 4; ++e) {
            int n = n0 + e;
            int lane = (n & 15) | (gg << 4);
            Fb[((size_t)(ks * 16 + (n >> 4)) * 64 + lane) * 8 + slot] = bfc(vals[e] * scale);
        }
    } else {
        int idx = ((bid - 128) * 256 + threadIdx.x) * 4;
#pragma unroll
        for (int e = 0; e < 4; ++e, ++idx) {
            int k = idx >> 7, n = idx & 127;
            float w = Wf[idx];
            us hi = bfc(w);
            us lo = bfc(w - bf2f(hi));
            int kk = k & 31;
            int g = (kk >> 2) & 3, b = kk >> 4, j0 = kk & 3;
            int lane = (n & 15) | (g << 4);
            size_t dst = ((size_t)((k >> 5) * 8 + (n >> 4)) * 64 + lane) * 8 + b * 4 + j0;
            WfpH[dst] = hi;
            WfpL[dst] = lo;
        }
    }
}

// ---------------- K2: projections via bf16 MFMA, 64-row tiles ---------------
__global__ __launch_bounds__(256, 6) void k_proj(const us* __restrict__ zn,
                                                 const us* __restrict__ F,
                                                 const float* __restrict__ bg,
                                                 us* __restrict__ Qf,
                                                 us* __restrict__ Kf,
                                                 us* __restrict__ Vtf,
                                                 us* __restrict__ Pg)
{
    const int rb = blockIdx.x, cb = blockIdx.y, t = threadIdx.x;
    const int m0 = rb * 64, n0 = cb * 128;
    const int mat = n0 >> 8, lc0 = n0 & 255;
    __shared__ us A[64][136];   // perm-k A tile; reused as C-stage

#pragma unroll
    for (int e = 0; e < 4; ++e) {
        int cid = e * 256 + t;
        int row = cid >> 4, c = cid & 15;
        uint4 q = *(const uint4*)(zn + (size_t)(m0 + row) * DD + c * 8);
        int ks = c >> 2, cc = c & 3;
        int fe = (cc & 1) * 16 + (cc >> 1) * 4;
        *(uint2*)&A[row][ks * 32 + fe]     = make_uint2(q.x, q.y);
        *(uint2*)&A[row][ks * 32 + fe + 8] = make_uint2(q.z, q.w);
    }
    __syncthreads();

    const int lane = t & 63, w = t >> 6;
    const int wm = w & 1, wn = w >> 1;
    const int l0 = lane & 15, g = lane >> 4;
    const us* Fb = F + mat * 32768 + ((size_t)((lc0 >> 4) + wn * 4) * 64 + lane) * 8;
    f32x4 acc[2][4];
#pragma unroll
    for (int a = 0; a < 2; ++a)
#pragma unroll
        for (int b = 0; b < 4; ++b) acc[a][b] = (f32x4){0, 0, 0, 0};

#pragma unroll
    for (int ks = 0; ks < 4; ++ks) {
        short8 af[2], bfr[4];
#pragma unroll
        for (int mf = 0; mf < 2; ++mf)
            af[mf] = *(const short8*)&A[wm * 32 + mf * 16 + l0][ks * 32 + 8 * g];
#pragma unroll
        for (int nf = 0; nf < 4; ++nf)
            bfr[nf] = *(const short8*)(Fb + (size_t)(ks * 16 + nf) * 512);
#pragma unroll
        for (int mf = 0; mf < 2; ++mf)
#pragma unroll
            for (int nf = 0; nf < 4; ++nf)
                acc[mf][nf] = __builtin_amdgcn_mfma_f32_16x16x32_bf16(af[mf], bfr[nf], acc[mf][nf], 0, 0, 0);
    }

    __syncthreads();   // all A reads done; reuse as C-stage (plain row/col)
    us (*Cs)[136] = A;
#pragma unroll
    for (int nf = 0; nf < 4; ++nf) {
        int lcol = wn * 64 + nf * 16 + l0;
        float bgv = (mat == 3) ? bg[lc0 + lcol] : 0.0f;
#pragma unroll
        for (int mf = 0; mf < 2; ++mf) {
#pragma unroll
            for (int r = 0; r < 4; ++r) {
                float v = acc[mf][nf][r];
                if (mat == 3) v = 1.0f / (1.0f + __expf(-(v + bgv)));
                Cs[wm * 32 + mf * 16 + 4 * g + r][lcol] = bfc(v);
            }
        }
    }
    __syncthreads();

    const int i = m0 >> 8;
    const int ktbase = (m0 & 255) >> 4;     // 0,4,8,12
    const int pbase  = (m0 & 255) >> 5;     // 0,2,4,6
    if (mat <= 1) {
        us* Dst = (mat == 0) ? Qf : Kf;
#pragma unroll
        for (int e = 0; e < 4; ++e) {
            int sub = e * 256 + t;                  // 0..1023
            int lane2 = sub & 63;
            int l0b = lane2 & 15, gb = lane2 >> 4;
            int rest = sub >> 6;                    // 0..15
            int hl = rest & 3, ktl = rest >> 2;     // 4 heads, 4 kt
            int hglob = (lc0 >> 5) + hl;
            int kt = ktbase + ktl;
            short8 vv = *(const short8*)&Cs[ktl * 16 + l0b][hl * 32 + 8 * gb];
            *(short8*)(Dst + (((size_t)(i * 8 + hglob) * 16 + kt) * 64 + lane2) * 8) = vv;
        }
    } else if (mat == 2) {
#pragma unroll
        for (int e = 0; e < 4; ++e) {
            int sub = e * 256 + t;                  // 0..1023
            int lane2 = sub & 63;
            int l0b = lane2 & 15, gb = lane2 >> 4;
            int rest = sub >> 6;                    // 0..15
            int ct = rest & 1, pl = (rest >> 1) & 1, hl = rest >> 2;
            int hglob = (lc0 >> 5) + hl;
            int p = pbase + pl;
            int col = hl * 32 + ct * 16 + l0b;
            us vals[8];
#pragma unroll
            for (int j = 0; j < 8; ++j) {
                int kk = 4 * gb + (j & 3) + 16 * (j >> 2);
                vals[j] = Cs[pl * 32 + kk][col];
            }
            *(short8*)(Vtf + ((((size_t)(i * 8 + hglob) * 8 + p) * 2 + ct) * 64 + lane2) * 8)
                = *(short8*)vals;
        }
    } else {
#pragma unroll
        for (int e = 0; e < 4; ++e) {
            int cid = e * 256 + t;
            int row = cid >> 4, c = cid & 15;
            short8 vv = *(const short8*)&Cs[row][c * 8];
            *(short8*)(Pg + (size_t)(m0 + row) * 256 + lc0 + c * 8) = vv;
        }
    }
}

// ---------------- K3: MFMA attention (pair-adjacent grid, K+V in LDS) -------
// Grid 2048: qh = (bx>>3)&1, ihid = (bx&7)|((bx>>4)<<3).
__global__ __launch_bounds__(256) void k_attn(const us* __restrict__ Qf,
                                              const us* __restrict__ Kf,
                                              const us* __restrict__ Vtf,
                                              const us* __restrict__ Pg,
                                              us* __restrict__ Po,
                                              const float* __restrict__ djk,
                                              const float* __restrict__ Wd,
                                              const float* __restrict__ mask)
{
    const int bx = blockIdx.x;
    const int qh = (bx >> 3) & 1;
    const int ih = (bx & 7) | ((bx >> 4) << 3);
    const int i = ih >> 3, h = ih & 7;
    const int t = threadIdx.x;
    const int lane = t & 63, w = t >> 6;
    const int l0 = lane & 15, g = lane >> 4;
    const int q0 = qh * 128 + w * 32;

    __shared__ us Kl[16 * 512];     // 16 K-frag tiles, linear (16KB); reused as gs
    __shared__ us Vl[16 * 512];     // 16 V-frag tiles, linear (16KB)
    __shared__ float madd[LL];      // log2e-scaled mask bias

    const us* Kb = Kf + (size_t)ih * 8192;
    const us* Vb = Vtf + (size_t)ih * 8192;

    // stage K+V: wave w -> tiles 4w..4w+3 of each (async direct-to-LDS)
    {
        int tile = w * 4;
        gload_lds16(Kb + (size_t)tile * 512 + lane * 8, &Kl[tile * 512]);
        gload_lds16(Kb + (size_t)(tile + 1) * 512 + lane * 8, &Kl[(tile + 1) * 512]);
        gload_lds16(Kb + (size_t)(tile + 2) * 512 + lane * 8, &Kl[(tile + 2) * 512]);
        gload_lds16(Kb + (size_t)(tile + 3) * 512 + lane * 8, &Kl[(tile + 3) * 512]);
        gload_lds16(Vb + (size_t)tile * 512 + lane * 8, &Vl[tile * 512]);
        gload_lds16(Vb + (size_t)(tile + 1) * 512 + lane * 8, &Vl[(tile + 1) * 512]);
        gload_lds16(Vb + (size_t)(tile + 2) * 512 + lane * 8, &Vl[(tile + 2) * 512]);
        gload_lds16(Vb + (size_t)(tile + 3) * 512 + lane * 8, &Vl[(tile + 3) * 512]);
    }
    madd[t] = (LOG2E * 1e9f) * (mask[i * LL + t] - 1.0f);

    const float wd = Wd[h] * LOG2E;
    short8 qfr[2];
    int qrow[2];
    const float* djkq[2];
#pragma unroll
    for (int qt = 0; qt < 2; ++qt) {
        qfr[qt] = *(const short8*)(Qf + (size_t)ih * 8192 + ((size_t)((q0 >> 4) + qt) * 64 + lane) * 8);
        qrow[qt] = q0 + qt * 16 + l0;
        djkq[qt] = djk + (size_t)qrow[qt] * LL;
    }
    __syncthreads();

    f32x4 oacc[2][2];
#pragma unroll
    for (int ct = 0; ct < 2; ++ct)
#pragma unroll
        for (int qt = 0; qt < 2; ++qt) oacc[ct][qt] = (f32x4){0, 0, 0, 0};
    float ssum[2] = {0, 0};

    for (int p = 0; p < 8; ++p) {
        short8 pfv[2];
#pragma unroll
        for (int hf = 0; hf < 2; ++hf) {
            const int kt = 2 * p + hf;
            short8 kfr = *(const short8*)&Kl[kt * 512 + lane * 8];
            f32x4 mvv = *(const f32x4*)&madd[kt * 16 + 4 * g];
#pragma unroll
            for (int qt = 0; qt < 2; ++qt) {
                f32x4 z4 = {0, 0, 0, 0};
                f32x4 s = __builtin_amdgcn_mfma_f32_16x16x32_bf16(kfr, qfr[qt], z4, 0, 0, 0);
                f32x4 dv = *(const f32x4*)(djkq[qt] + kt * 16 + 4 * g);
                float p0 = __builtin_amdgcn_exp2f(s[0] + wd * dv.x + mvv.x);
                float p1 = __builtin_amdgcn_exp2f(s[1] + wd * dv.y + mvv.y);
                float p2 = __builtin_amdgcn_exp2f(s[2] + wd * dv.z + mvv.z);
                float p3 = __builtin_amdgcn_exp2f(s[3] + wd * dv.w + mvv.w);
                ssum[qt] += (p0 + p1) + (p2 + p3);
                pfv[qt][hf * 4 + 0] = (short)bfc(p0);
                pfv[qt][hf * 4 + 1] = (short)bfc(p1);
                pfv[qt][hf * 4 + 2] = (short)bfc(p2);
                pfv[qt][hf * 4 + 3] = (short)bfc(p3);
            }
        }
#pragma unroll
        for (int ct = 0; ct < 2; ++ct) {
            short8 vfr = *(const short8*)&Vl[(p * 2 + ct) * 512 + lane * 8];
#pragma unroll
            for (int qt = 0; qt < 2; ++qt)
                oacc[ct][qt] = __builtin_amdgcn_mfma_f32_16x16x32_bf16(vfr, pfv[qt], oacc[ct][qt], 0, 0, 0);
        }
    }

    // epilogue: row sums, gate, LDS transpose (reuse Kl), head-major write
    __syncthreads();   // all Kl/Vl reads complete before reuse
    us (*gs)[40] = (us (*)[40])Kl;
#pragma unroll
    for (int qt = 0; qt < 2; ++qt) {
        float s = ssum[qt];
        s += __shfl_xor(s, 16, 64);
        s += __shfl_xor(s, 32, 64);
        float inv = 1.0f / s;
        const us* gb = Pg + (size_t)(i * LL + qrow[qt]) * 256 + h * CC;
#pragma unroll
        for (int ct = 0; ct < 2; ++ct) {
            short4v gv = *(const short4v*)(gb + ct * 16 + 4 * g);
            f32x4 ov = oacc[ct][qt];
            short4v res;
            res.x = (short)bfc(bf2f((us)gv.x) * ov.x * inv);
            res.y = (short)bfc(bf2f((us)gv.y) * ov.y * inv);
            res.z = (short)bfc(bf2f((us)gv.z) * ov.z * inv);
            res.w = (short)bfc(bf2f((us)gv.w) * ov.w * inv);
            *(short4v*)&gs[w * 32 + qt * 16 + l0][ct * 16 + 4 * g] = res;
        }
    }
    __syncthreads();
#pragma unroll
    for (int e = 0; e < 2; ++e) {
        int cid = e * 256 + t;           // 0..511
        int row = cid >> 2, c = cid & 3;
        short8 vv = *(const short8*)&gs[row][c * 8];
        *(short8*)(Po + ((size_t)h * NROW + (size_t)i * LL + qh * 128 + row) * 32 + c * 8) = vv;
    }
}

// ---------------- K4: out = gated @ (WfH + WfL) + bf, x mask (MFMA) ---------
// Po is head-major: Po[h][grow][32].
__global__ __launch_bounds__(256) void k_out(const us* __restrict__ Po,
                                             const us* __restrict__ WfpH,
                                             const us* __restrict__ WfpL,
                                             const float* __restrict__ bf_,
                                             const float* __restrict__ mask,
                                             float* __restrict__ out)
{
    const int t = threadIdx.x;
    const int m0 = blockIdx.x * 64;
    __shared__ us A[64][264];
#pragma unroll
    for (int e = 0; e < 8; ++e) {
        int cid = e * 256 + t;
        int row = cid >> 5, c = cid & 31;          // c*8 = global k chunk
        int hh = c >> 2, cc = c & 3;               // head, chunk-within-head
        uint4 q = *(const uint4*)(Po + ((size_t)hh * NROW + m0 + row) * 32 + cc * 8);
        int ksb = c >> 2, cc2 = c & 3;
        int fe = (cc2 & 1) * 16 + (cc2 >> 1) * 4;
        *(uint2*)&A[row][ksb * 32 + fe]     = make_uint2(q.x, q.y);
        *(uint2*)&A[row][ksb * 32 + fe + 8] = make_uint2(q.z, q.w);
    }
    __syncthreads();
    const int lane = t & 63, w = t >> 6;
    const int l0 = lane & 15, g = lane >> 4;
    f32x4 acc[8];
#pragma unroll
    for (int nf = 0; nf < 8; ++nf) acc[nf] = (f32x4){0, 0, 0, 0};

#pragma unroll
    for (int ksb = 0; ksb < 8; ++ksb) {
        short8 af = *(const short8*)&A[w * 16 + l0][ksb * 32 + 8 * g];
#pragma unroll
        for (int nf = 0; nf < 8; ++nf) {
            short8 bh = *(const short8*)(WfpH + ((size_t)(ksb * 8 + nf) * 64 + lane) * 8);
            short8 bl = *(const short8*)(WfpL + ((size_t)(ksb * 8 + nf) * 64 + lane) * 8);
            acc[nf] = __builtin_amdgcn_mfma_f32_16x16x32_bf16(af, bh, acc[nf], 0, 0, 0);
            acc[nf] = __builtin_amdgcn_mfma_f32_16x16x32_bf16(af, bl, acc[nf], 0, 0, 0);
        }
    }
    float maskv[4];
    int rowm[4];
#pragma unroll
    for (int r = 0; r < 4; ++r) {
        rowm[r] = m0 + w * 16 + 4 * g + r;
        maskv[r] = mask[rowm[r]];
    }
#pragma unroll
    for (int nf = 0; nf < 8; ++nf) {
        int n = nf * 16 + l0;
        float bfv = bf_[n];
#pragma unroll
        for (int r = 0; r < 4; ++r)
            out[(size_t)rowm[r] * DD + n] = (acc[nf][r] + bfv) * maskv[r];
    }
}

extern "C" void kernel_launch(void* const* d_in, const int* in_sizes, int n_in,
                              void* d_out, int out_size, void* d_ws, size_t ws_size,
                              hipStream_t stream)
{
    const float* z     = (const float*)d_in[0];
    const float* djk   = (const float*)d_in[1];
    const float* mask  = (const float*)d_in[2];
    const float* gamma = (const float*)d_in[3];
    const float* beta  = (const float*)d_in[4];
    const float* Wq    = (const float*)d_in[5];
    const float* Wk    = (const float*)d_in[6];
    const float* Wv    = (const float*)d_in[7];
    // d_in[8] = Wb: constant along softmax axis -> cancels exactly.
    const float* Wd    = (const float*)d_in[9];
    const float* Wg    = (const float*)d_in[10];
    const float* bg    = (const float*)d_in[11];
    const float* Wf    = (const float*)d_in[12];
    const float* bf_   = (const float*)d_in[13];
    float* out = (float*)d_out;

    us* zn   = (us*)d_ws;                         // 8.4 MB
    us* Qf   = zn   + (size_t)NROW * DD;          // 16.8 MB
    us* Kf   = Qf   + (size_t)1024 * 8192;        // 16.8 MB
    us* Vtf  = Kf   + (size_t)1024 * 8192;        // 16.8 MB
    us* Pg   = Vtf  + (size_t)1024 * 8192;        // 16.8 MB
    us* Po   = Pg   + (size_t)NROW * 256;         // 16.8 MB (head-major)
    us* WfpH = Po   + (size_t)NROW * 256;         // 64 KB
    us* WfpL = WfpH + 256 * 128;                  // 64 KB
    us* F    = WfpL + 256 * 128;                  // 256 KB

    k_ln   <<<NROW / 4, 256, 0, stream>>>(z, gamma, beta, zn);
    k_wprep<<<160, 256, 0, stream>>>(Wq, Wk, Wv, Wg, Wf, F, WfpH, WfpL);
    k_proj <<<dim3(NROW / 64, 8), 256, 0, stream>>>(zn, F, bg, Qf, Kf, Vtf, Pg);
    k_attn <<<2048, 256, 0, stream>>>(Qf, Kf, Vtf, Pg, Po, djk, Wd, mask);
    k_out  <<<NROW / 64, 256, 0, stream>>>(Po, WfpH, WfpL, bf_, mask, out);
}

// Round 19
// 88.135 us; speedup vs baseline: 1.0767x; 1.0160x over previous
//
#include <hip/hip_runtime.h>
#include <hip/hip_bf16.h>
#include <math.h>

#define HH 8
#define CC 32
#define DD 128
#define HC 256
#define II 128
#define LL 256
#define NROW (II*LL)   // 32768
#define LN_EPS 1e-5f
#define LOG2E 1.4426950408889634f

typedef float f32x4 __attribute__((ext_vector_type(4)));
typedef short short8 __attribute__((ext_vector_type(8)));
typedef short short4v __attribute__((ext_vector_type(4)));
typedef unsigned short us;

static __device__ __forceinline__ us bfc(float x) {
    return __builtin_bit_cast(us, __float2bfloat16(x));
}
static __device__ __forceinline__ float bf2f(us h) {
    return __builtin_bit_cast(float, ((unsigned int)h) << 16);
}
// global -> LDS async 16B/lane; LDS dest = uniform base + lane*16 (linear).
static __device__ __forceinline__ void gload_lds16(const us* g, us* l) {
    __builtin_amdgcn_global_load_lds(
        (const __attribute__((address_space(1))) unsigned int*)g,
        (__attribute__((address_space(3))) unsigned int*)l,
        16, 0, 0);
}

// ---------------- K1: fused LayerNorm (blocks 0..8191) + weight prep --------
// blocks 8192..8319: Wq/Wk/Wv/Wg -> MFMA B-frag layout (Wq scaled by LOG2E/sqrt(H))
// blocks 8320..8351: Wf -> hi/lo split frags.
__global__ __launch_bounds__(256) void k_prep(const float* __restrict__ z,
                                              const float* __restrict__ gamma,
                                              const float* __restrict__ beta,
                                              const float* __restrict__ Wq,
                                              const float* __restrict__ Wk,
                                              const float* __restrict__ Wv,
                                              const float* __restrict__ Wg,
                                              const float* __restrict__ Wf,
                                              us* __restrict__ zn,
                                              us* __restrict__ F,
                                              us* __restrict__ WfpH,
                                              us* __restrict__ WfpL)
{
    const int bid = blockIdx.x;
    const int t = threadIdx.x;
    if (bid < 8192) {
        const int row = bid * 4 + (t >> 6);
        const int lane = t & 63;
        float2 x = *(const float2*)(z + (size_t)row * DD + lane * 2);
        float s = x.x + x.y;
        float s2 = x.x * x.x + x.y * x.y;
#pragma unroll
        for (int off = 1; off < 64; off <<= 1) {
            s  += __shfl_xor(s, off, 64);
            s2 += __shfl_xor(s2, off, 64);
        }
        float mu = s * (1.0f / DD);
        float var = s2 * (1.0f / DD) - mu * mu;
        float rstd = rsqrtf(var + LN_EPS);
        float2 gm = *(const float2*)(gamma + lane * 2);
        float2 bt = *(const float2*)(beta + lane * 2);
        float y0 = (x.x - mu) * rstd * gm.x + bt.x;
        float y1 = (x.y - mu) * rstd * gm.y + bt.y;
        unsigned int pk = (unsigned int)bfc(y0) | ((unsigned int)bfc(y1) << 16);
        ((unsigned int*)zn)[(size_t)row * 64 + lane] = pk;
    } else if (bid < 8320) {
        const int wb = bid - 8192;          // 0..127
        const int mat = wb >> 5;
        const float* W = (mat == 0) ? Wq : (mat == 1) ? Wk : (mat == 2) ? Wv : Wg;
        const float scale = (mat == 0) ? 0.35355339059327373f * LOG2E : 1.0f;
        int base = (wb & 31) * 1024 + t * 4;
        float4 wv = *(const float4*)(W + base);
        int k = base >> 8, n0 = base & 255;
        int ks = k >> 5, kk = k & 31;
        int slot = ((kk >> 4) << 2) | (kk & 3);
        int gg = (kk >> 2) & 3;
        float vals[4] = {wv.x, wv.y, wv.z, wv.w};
        us* Fb = F + mat * 32768;
#pragma unroll
        for (int e = 0; e < 4; ++e) {
            int n = n0 + e;
            int lane = (n & 15) | (gg << 4);
            Fb[((size_t)(ks * 16 + (n >> 4)) * 64 + lane) * 8 + slot] = bfc(vals[e] * scale);
        }
    } else {
        int idx = ((bid - 8320) * 256 + t) * 4;
#pragma unroll
        for (int e = 0; e < 4; ++e, ++idx) {
            int k = idx >> 7, n = idx & 127;
            float w = Wf[idx];
            us hi = bfc(w);
            us lo = bfc(w - bf2f(hi));
            int kk = k & 31;
            int g = (kk >> 2) & 3, b = kk >> 4, j0 = kk & 3;
            int lane = (n & 15) | (g << 4);
            size_t dst = ((size_t)((k >> 5) * 8 + (n >> 4)) * 64 + lane) * 8 + b * 4 + j0;
            WfpH[dst] = hi;
            WfpL[dst] = lo;
        }
    }
}

// ---------------- K2: projections via bf16 MFMA, 64-row tiles ---------------
__global__ __launch_bounds__(256, 6) void k_proj(const us* __restrict__ zn,
                                                 const us* __restrict__ F,
                                                 const float* __restrict__ bg,
                                                 us* __restrict__ Qf,
                                                 us* __restrict__ Kf,
                                                 us* __restrict__ Vtf,
                                                 us* __restrict__ Pg)
{
    const int rb = blockIdx.x, cb = blockIdx.y, t = threadIdx.x;
    const int m0 = rb * 64, n0 = cb * 128;
    const int mat = n0 >> 8, lc0 = n0 & 255;
    __shared__ us A[64][136];   // perm-k A tile; reused as C-stage

#pragma unroll
    for (int e = 0; e < 4; ++e) {
        int cid = e * 256 + t;
        int row = cid >> 4, c = cid & 15;
        uint4 q = *(const uint4*)(zn + (size_t)(m0 + row) * DD + c * 8);
        int ks = c >> 2, cc = c & 3;
        int fe = (cc & 1) * 16 + (cc >> 1) * 4;
        *(uint2*)&A[row][ks * 32 + fe]     = make_uint2(q.x, q.y);
        *(uint2*)&A[row][ks * 32 + fe + 8] = make_uint2(q.z, q.w);
    }
    __syncthreads();

    const int lane = t & 63, w = t >> 6;
    const int wm = w & 1, wn = w >> 1;
    const int l0 = lane & 15, g = lane >> 4;
    const us* Fb = F + mat * 32768 + ((size_t)((lc0 >> 4) + wn * 4) * 64 + lane) * 8;
    f32x4 acc[2][4];
#pragma unroll
    for (int a = 0; a < 2; ++a)
#pragma unroll
        for (int b = 0; b < 4; ++b) acc[a][b] = (f32x4){0, 0, 0, 0};

#pragma unroll
    for (int ks = 0; ks < 4; ++ks) {
        short8 af[2], bfr[4];
#pragma unroll
        for (int mf = 0; mf < 2; ++mf)
            af[mf] = *(const short8*)&A[wm * 32 + mf * 16 + l0][ks * 32 + 8 * g];
#pragma unroll
        for (int nf = 0; nf < 4; ++nf)
            bfr[nf] = *(const short8*)(Fb + (size_t)(ks * 16 + nf) * 512);
#pragma unroll
        for (int mf = 0; mf < 2; ++mf)
#pragma unroll
            for (int nf = 0; nf < 4; ++nf)
                acc[mf][nf] = __builtin_amdgcn_mfma_f32_16x16x32_bf16(af[mf], bfr[nf], acc[mf][nf], 0, 0, 0);
    }

    __syncthreads();   // all A reads done; reuse as C-stage (plain row/col)
    us (*Cs)[136] = A;
#pragma unroll
    for (int nf = 0; nf < 4; ++nf) {
        int lcol = wn * 64 + nf * 16 + l0;
        float bgv = (mat == 3) ? bg[lc0 + lcol] : 0.0f;
#pragma unroll
        for (int mf = 0; mf < 2; ++mf) {
#pragma unroll
            for (int r = 0; r < 4; ++r) {
                float v = acc[mf][nf][r];
                if (mat == 3) v = 1.0f / (1.0f + __expf(-(v + bgv)));
                Cs[wm * 32 + mf * 16 + 4 * g + r][lcol] = bfc(v);
            }
        }
    }
    __syncthreads();

    const int i = m0 >> 8;
    const int ktbase = (m0 & 255) >> 4;     // 0,4,8,12
    const int pbase  = (m0 & 255) >> 5;     // 0,2,4,6
    if (mat <= 1) {
        us* Dst = (mat == 0) ? Qf : Kf;
#pragma unroll
        for (int e = 0; e < 4; ++e) {
            int sub = e * 256 + t;                  // 0..1023
            int lane2 = sub & 63;
            int l0b = lane2 & 15, gb = lane2 >> 4;
            int rest = sub >> 6;                    // 0..15
            int hl = rest & 3, ktl = rest >> 2;     // 4 heads, 4 kt
            int hglob = (lc0 >> 5) + hl;
            int kt = ktbase + ktl;
            short8 vv = *(const short8*)&Cs[ktl * 16 + l0b][hl * 32 + 8 * gb];
            *(short8*)(Dst + (((size_t)(i * 8 + hglob) * 16 + kt) * 64 + lane2) * 8) = vv;
        }
    } else if (mat == 2) {
#pragma unroll
        for (int e = 0; e < 4; ++e) {
            int sub = e * 256 + t;                  // 0..1023
            int lane2 = sub & 63;
            int l0b = lane2 & 15, gb = lane2 >> 4;
            int rest = sub >> 6;                    // 0..15
            int ct = rest & 1, pl = (rest >> 1) & 1, hl = rest >> 2;
            int hglob = (lc0 >> 5) + hl;
            int p = pbase + pl;
            int col = hl * 32 + ct * 16 + l0b;
            us vals[8];
#pragma unroll
            for (int j = 0; j < 8; ++j) {
                int kk = 4 * gb + (j & 3) + 16 * (j >> 2);
                vals[j] = Cs[pl * 32 + kk][col];
            }
            *(short8*)(Vtf + ((((size_t)(i * 8 + hglob) * 8 + p) * 2 + ct) * 64 + lane2) * 8)
                = *(short8*)vals;
        }
    } else {
#pragma unroll
        for (int e = 0; e < 4; ++e) {
            int cid = e * 256 + t;
            int row = cid >> 4, c = cid & 15;
            short8 vv = *(const short8*)&Cs[row][c * 8];
            *(short8*)(Pg + (size_t)(m0 + row) * 256 + lc0 + c * 8) = vv;
        }
    }
}

// ---------------- K3: MFMA attention (pair-adjacent grid, K+V in LDS) -------
// Grid 2048: qh = (bx>>3)&1, ihid = (bx&7)|((bx>>4)<<3).
__global__ __launch_bounds__(256) void k_attn(const us* __restrict__ Qf,
                                              const us* __restrict__ Kf,
                                              const us* __restrict__ Vtf,
                                              const us* __restrict__ Pg,
                                              us* __restrict__ Po,
                                              const float* __restrict__ djk,
                                              const float* __restrict__ Wd,
                                              const float* __restrict__ mask)
{
    const int bx = blockIdx.x;
    const int qh = (bx >> 3) & 1;
    const int ih = (bx & 7) | ((bx >> 4) << 3);
    const int i = ih >> 3, h = ih & 7;
    const int t = threadIdx.x;
    const int lane = t & 63, w = t >> 6;
    const int l0 = lane & 15, g = lane >> 4;
    const int q0 = qh * 128 + w * 32;

    __shared__ us Kl[16 * 512];     // 16 K-frag tiles, linear (16KB); reused as gs
    __shared__ us Vl[16 * 512];     // 16 V-frag tiles, linear (16KB)
    __shared__ float madd[LL];      // log2e-scaled mask bias

    const us* Kb = Kf + (size_t)ih * 8192;
    const us* Vb = Vtf + (size_t)ih * 8192;

    // stage K+V: wave w -> tiles 4w..4w+3 of each (async direct-to-LDS)
    {
        int tile = w * 4;
        gload_lds16(Kb + (size_t)tile * 512 + lane * 8, &Kl[tile * 512]);
        gload_lds16(Kb + (size_t)(tile + 1) * 512 + lane * 8, &Kl[(tile + 1) * 512]);
        gload_lds16(Kb + (size_t)(tile + 2) * 512 + lane * 8, &Kl[(tile + 2) * 512]);
        gload_lds16(Kb + (size_t)(tile + 3) * 512 + lane * 8, &Kl[(tile + 3) * 512]);
        gload_lds16(Vb + (size_t)tile * 512 + lane * 8, &Vl[tile * 512]);
        gload_lds16(Vb + (size_t)(tile + 1) * 512 + lane * 8, &Vl[(tile + 1) * 512]);
        gload_lds16(Vb + (size_t)(tile + 2) * 512 + lane * 8, &Vl[(tile + 2) * 512]);
        gload_lds16(Vb + (size_t)(tile + 3) * 512 + lane * 8, &Vl[(tile + 3) * 512]);
    }
    madd[t] = (LOG2E * 1e9f) * (mask[i * LL + t] - 1.0f);

    const float wd = Wd[h] * LOG2E;
    short8 qfr[2];
    int qrow[2];
    const float* djkq[2];
#pragma unroll
    for (int qt = 0; qt < 2; ++qt) {
        qfr[qt] = *(const short8*)(Qf + (size_t)ih * 8192 + ((size_t)((q0 >> 4) + qt) * 64 + lane) * 8);
        qrow[qt] = q0 + qt * 16 + l0;
        djkq[qt] = djk + (size_t)qrow[qt] * LL;
    }
    __syncthreads();

    f32x4 oacc[2][2];
#pragma unroll
    for (int ct = 0; ct < 2; ++ct)
#pragma unroll
        for (int qt = 0; qt < 2; ++qt) oacc[ct][qt] = (f32x4){0, 0, 0, 0};
    float ssum[2] = {0, 0};

    for (int p = 0; p < 8; ++p) {
        short8 pfv[2];
#pragma unroll
        for (int hf = 0; hf < 2; ++hf) {
            const int kt = 2 * p + hf;
            short8 kfr = *(const short8*)&Kl[kt * 512 + lane * 8];
            f32x4 mvv = *(const f32x4*)&madd[kt * 16 + 4 * g];
#pragma unroll
            for (int qt = 0; qt < 2; ++qt) {
                f32x4 z4 = {0, 0, 0, 0};
                f32x4 s = __builtin_amdgcn_mfma_f32_16x16x32_bf16(kfr, qfr[qt], z4, 0, 0, 0);
                f32x4 dv = *(const f32x4*)(djkq[qt] + kt * 16 + 4 * g);
                float p0 = __builtin_amdgcn_exp2f(s[0] + wd * dv.x + mvv.x);
                float p1 = __builtin_amdgcn_exp2f(s[1] + wd * dv.y + mvv.y);
                float p2 = __builtin_amdgcn_exp2f(s[2] + wd * dv.z + mvv.z);
                float p3 = __builtin_amdgcn_exp2f(s[3] + wd * dv.w + mvv.w);
                ssum[qt] += (p0 + p1) + (p2 + p3);
                pfv[qt][hf * 4 + 0] = (short)bfc(p0);
                pfv[qt][hf * 4 + 1] = (short)bfc(p1);
                pfv[qt][hf * 4 + 2] = (short)bfc(p2);
                pfv[qt][hf * 4 + 3] = (short)bfc(p3);
            }
        }
#pragma unroll
        for (int ct = 0; ct < 2; ++ct) {
            short8 vfr = *(const short8*)&Vl[(p * 2 + ct) * 512 + lane * 8];
#pragma unroll
            for (int qt = 0; qt < 2; ++qt)
                oacc[ct][qt] = __builtin_amdgcn_mfma_f32_16x16x32_bf16(vfr, pfv[qt], oacc[ct][qt], 0, 0, 0);
        }
    }

    // epilogue: row sums, gate, LDS transpose (reuse Kl), head-major write
    __syncthreads();   // all Kl/Vl reads complete before reuse
    us (*gs)[40] = (us (*)[40])Kl;
#pragma unroll
    for (int qt = 0; qt < 2; ++qt) {
        float s = ssum[qt];
        s += __shfl_xor(s, 16, 64);
        s += __shfl_xor(s, 32, 64);
        float inv = 1.0f / s;
        const us* gb = Pg + (size_t)(i * LL + qrow[qt]) * 256 + h * CC;
#pragma unroll
        for (int ct = 0; ct < 2; ++ct) {
            short4v gv = *(const short4v*)(gb + ct * 16 + 4 * g);
            f32x4 ov = oacc[ct][qt];
            short4v res;
            res.x = (short)bfc(bf2f((us)gv.x) * ov.x * inv);
            res.y = (short)bfc(bf2f((us)gv.y) * ov.y * inv);
            res.z = (short)bfc(bf2f((us)gv.z) * ov.z * inv);
            res.w = (short)bfc(bf2f((us)gv.w) * ov.w * inv);
            *(short4v*)&gs[w * 32 + qt * 16 + l0][ct * 16 + 4 * g] = res;
        }
    }
    __syncthreads();
#pragma unroll
    for (int e = 0; e < 2; ++e) {
        int cid = e * 256 + t;           // 0..511
        int row = cid >> 2, c = cid & 3;
        short8 vv = *(const short8*)&gs[row][c * 8];
        *(short8*)(Po + ((size_t)h * NROW + (size_t)i * LL + qh * 128 + row) * 32 + c * 8) = vv;
    }
}

// ---------------- K4: out = gated @ (WfH + WfL) + bf, x mask (MFMA) ---------
// Po is head-major: Po[h][grow][32].
__global__ __launch_bounds__(256) void k_out(const us* __restrict__ Po,
                                             const us* __restrict__ WfpH,
                                             const us* __restrict__ WfpL,
                                             const float* __restrict__ bf_,
                                             const float* __restrict__ mask,
                                             float* __restrict__ out)
{
    const int t = threadIdx.x;
    const int m0 = blockIdx.x * 64;
    __shared__ us A[64][264];
#pragma unroll
    for (int e = 0; e < 8; ++e) {
        int cid = e * 256 + t;
        int row = cid >> 5, c = cid & 31;          // c*8 = global k chunk
        int hh = c >> 2, cc = c & 3;               // head, chunk-within-head
        uint4 q = *(const uint4*)(Po + ((size_t)hh * NROW + m0 + row) * 32 + cc * 8);
        int ksb = c >> 2, cc2 = c & 3;
        int fe = (cc2 & 1) * 16 + (cc2 >> 1) * 4;
        *(uint2*)&A[row][ksb * 32 + fe]     = make_uint2(q.x, q.y);
        *(uint2*)&A[row][ksb * 32 + fe + 8] = make_uint2(q.z, q.w);
    }
    __syncthreads();
    const int lane = t & 63, w = t >> 6;
    const int l0 = lane & 15, g = lane >> 4;
    f32x4 acc[8];
#pragma unroll
    for (int nf = 0; nf < 8; ++nf) acc[nf] = (f32x4){0, 0, 0, 0};

#pragma unroll
    for (int ksb = 0; ksb < 8; ++ksb) {
        short8 af = *(const short8*)&A[w * 16 + l0][ksb * 32 + 8 * g];
#pragma unroll
        for (int nf = 0; nf < 8; ++nf) {
            short8 bh = *(const short8*)(WfpH + ((size_t)(ksb * 8 + nf) * 64 + lane) * 8);
            short8 bl = *(const short8*)(WfpL + ((size_t)(ksb * 8 + nf) * 64 + lane) * 8);
            acc[nf] = __builtin_amdgcn_mfma_f32_16x16x32_bf16(af, bh, acc[nf], 0, 0, 0);
            acc[nf] = __builtin_amdgcn_mfma_f32_16x16x32_bf16(af, bl, acc[nf], 0, 0, 0);
        }
    }
    float maskv[4];
    int rowm[4];
#pragma unroll
    for (int r = 0; r < 4; ++r) {
        rowm[r] = m0 + w * 16 + 4 * g + r;
        maskv[r] = mask[rowm[r]];
    }
#pragma unroll
    for (int nf = 0; nf < 8; ++nf) {
        int n = nf * 16 + l0;
        float bfv = bf_[n];
#pragma unroll
        for (int r = 0; r < 4; ++r)
            out[(size_t)rowm[r] * DD + n] = (acc[nf][r] + bfv) * maskv[r];
    }
}

extern "C" void kernel_launch(void* const* d_in, const int* in_sizes, int n_in,
                              void* d_out, int out_size, void* d_ws, size_t ws_size,
                              hipStream_t stream)
{
    const float* z     = (const float*)d_in[0];
    const float* djk   = (const float*)d_in[1];
    const float* mask  = (const float*)d_in[2];
    const float* gamma = (const float*)d_in[3];
    const float* beta  = (const float*)d_in[4];
    const float* Wq    = (const float*)d_in[5];
    const float* Wk    = (const float*)d_in[6];
    const float* Wv    = (const float*)d_in[7];
    // d_in[8] = Wb: constant along softmax axis -> cancels exactly.
    const float* Wd    = (const float*)d_in[9];
    const float* Wg    = (const float*)d_in[10];
    const float* bg    = (const float*)d_in[11];
    const float* Wf    = (const float*)d_in[12];
    const float* bf_   = (const float*)d_in[13];
    float* out = (float*)d_out;

    us* zn   = (us*)d_ws;                         // 8.4 MB
    us* Qf   = zn   + (size_t)NROW * DD;          // 16.8 MB
    us* Kf   = Qf   + (size_t)1024 * 8192;        // 16.8 MB
    us* Vtf  = Kf   + (size_t)1024 * 8192;        // 16.8 MB
    us* Pg   = Vtf  + (size_t)1024 * 8192;        // 16.8 MB
    us* Po   = Pg   + (size_t)NROW * 256;         // 16.8 MB (head-major)
    us* WfpH = Po   + (size_t)NROW * 256;         // 64 KB
    us* WfpL = WfpH + 256 * 128;                  // 64 KB
    us* F    = WfpL + 256 * 128;                  // 256 KB

    k_prep <<<8352, 256, 0, stream>>>(z, gamma, beta, Wq, Wk, Wv, Wg, Wf,
                                      zn, F, WfpH, WfpL);
    k_proj <<<dim3(NROW / 64, 8), 256, 0, stream>>>(zn, F, bg, Qf, Kf, Vtf, Pg);
    k_attn <<<2048, 256, 0, stream>>>(Qf, Kf, Vtf, Pg, Po, djk, Wd, mask);
    k_out  <<<NROW / 64, 256, 0, stream>>>(Po, WfpH, WfpL, bf_, mask, out);
}